// Round 1
// baseline (138.910 us; speedup 1.0000x reference)
//
#include <hip/hip_runtime.h>
#include <math.h>

// GNLoss: 4-level pyramid, triplet + Gauss-Newton loss over 8192 sample points.
// Key algorithmic move: never materialize grad2d(fb) — compute Jx/Jy from the
// fb stencil at the 4 bilinear corners directly (central diff w/ edge clamp).

struct BL { int x0, x1, y0, y1; float wx, wy; };

__device__ __forceinline__ BL bl_setup(float px, float py, int W, int H) {
    BL r;
    float x = fminf(fmaxf(px, 0.0f), (float)(W - 1));
    float y = fminf(fmaxf(py, 0.0f), (float)(H - 1));
    float fx = floorf(x), fy = floorf(y);
    r.wx = x - fx; r.wy = y - fy;
    r.x0 = (int)fx; r.y0 = (int)fy;
    r.x1 = min(r.x0 + 1, W - 1);
    r.y1 = min(r.y0 + 1, H - 1);
    return r;
}

__device__ __forceinline__ float bl_eval(const float* __restrict__ f, int W, const BL& s) {
    float v00 = f[s.y0 * W + s.x0];
    float v01 = f[s.y0 * W + s.x1];
    float v10 = f[s.y1 * W + s.x0];
    float v11 = f[s.y1 * W + s.x1];
    float w00 = (1.0f - s.wx) * (1.0f - s.wy);
    float w01 = s.wx * (1.0f - s.wy);
    float w10 = (1.0f - s.wx) * s.wy;
    float w11 = s.wx * s.wy;
    return v00 * w00 + v01 * w01 + v10 * w10 + v11 * w11;
}

// Jx = bilinear(gx, xs), Jy = bilinear(gy, xs) where gx,gy are central
// differences of f with edge replication — evaluated from f directly.
__device__ __forceinline__ void j_eval(const float* __restrict__ f, int W, int H,
                                       const BL& s, float& Jx, float& Jy) {
    int xR0 = min(s.x0 + 1, W - 1), xL0 = max(s.x0 - 1, 0);
    int xR1 = min(s.x1 + 1, W - 1), xL1 = max(s.x1 - 1, 0);
    int yD0 = min(s.y0 + 1, H - 1), yU0 = max(s.y0 - 1, 0);
    int yD1 = min(s.y1 + 1, H - 1), yU1 = max(s.y1 - 1, 0);
    const float* r0 = f + s.y0 * W;
    const float* r1 = f + s.y1 * W;
    float gx00 = r0[xR0] - r0[xL0];
    float gx01 = r0[xR1] - r0[xL1];
    float gx10 = r1[xR0] - r1[xL0];
    float gx11 = r1[xR1] - r1[xL1];
    float gy00 = f[yD0 * W + s.x0] - f[yU0 * W + s.x0];
    float gy01 = f[yD0 * W + s.x1] - f[yU0 * W + s.x1];
    float gy10 = f[yD1 * W + s.x0] - f[yU1 * W + s.x0];
    float gy11 = f[yD1 * W + s.x1] - f[yU1 * W + s.x1];
    float w00 = (1.0f - s.wx) * (1.0f - s.wy);
    float w01 = s.wx * (1.0f - s.wy);
    float w10 = (1.0f - s.wx) * s.wy;
    float w11 = s.wx * s.wy;
    Jx = 0.5f * (gx00 * w00 + gx01 * w01 + gx10 * w10 + gx11 * w11);
    Jy = 0.5f * (gy00 * w00 + gy01 * w01 + gy10 * w10 + gy11 * w11);
}

__device__ __forceinline__ float warp32_sum(float v) {
    v += __shfl_xor(v, 16);
    v += __shfl_xor(v, 8);
    v += __shfl_xor(v, 4);
    v += __shfl_xor(v, 2);
    v += __shfl_xor(v, 1);
    return v;
}

// One block = 8 points x 32 channels (lane = channel). Grid = 1024 blocks/level.
__global__ __launch_bounds__(256) void gn_level_kernel(
    const float* __restrict__ fa, const float* __restrict__ fb,
    const float* __restrict__ noise, const float* __restrict__ ma,
    const float* __restrict__ mb, const float* __restrict__ ng,
    int H, float inv_s, float* __restrict__ blk_out) {
    const int W = H;
    const int tid = threadIdx.x;
    const int c = tid & 31;        // channel
    const int pib = tid >> 5;      // point-in-block 0..7
    const int p = blockIdx.x * 8 + pib;  // global point 0..8191 (= b*2048+n)
    const int b = p >> 11;
    const int HW = H * W;
    const float* __restrict__ fac = fa + (size_t)(b * 32 + c) * HW;
    const float* __restrict__ fbc = fb + (size_t)(b * 32 + c) * HW;

    const int p2 = p * 2;
    const float nzx = noise[p2], nzy = noise[p2 + 1];
    const float pax = ma[p2] * inv_s, pay = ma[p2 + 1] * inv_s;
    const float pbx = mb[p2] * inv_s, pby = mb[p2 + 1] * inv_s;
    const float pnx = ng[p2] * inv_s, pny = ng[p2 + 1] * inv_s;
    const float xsx = nzx + pbx, xsy = nzy + pby;  // xs = noise + ub (unclipped)

    BL sa = bl_setup(pax, pay, W, H);
    BL sb = bl_setup(pbx, pby, W, H);
    BL sg = bl_setup(pnx, pny, W, H);
    BL sx = bl_setup(xsx, xsy, W, H);

    float fav = bl_eval(fac, W, sa);   // f_t / anchor
    float fpv = bl_eval(fbc, W, sb);   // positive
    float fnv = bl_eval(fbc, W, sg);   // negative
    float fsv = bl_eval(fbc, W, sx);   // f_s
    float Jx, Jy;
    j_eval(fbc, W, H, sx, Jx, Jy);

    float r = fsv - fav;
    float a  = warp32_sum(Jx * Jx);
    float dd = warp32_sum(Jy * Jy);
    float bb = warp32_sum(Jx * Jy);
    float bx = warp32_sum(Jx * r);
    float by = warp32_sum(Jy * r);
    float dfp = fav - fpv, dfn = fav - fnv;
    float sp = warp32_sum(dfp * dfp);
    float sn = warp32_sum(dfn * dfn);

    __shared__ float red[3][8];
    if (c == 0) {
        a += 1e-9f; dd += 1e-9f;
        float det = a * dd - bb * bb;          // > 0 by Cauchy-Schwarz + eps
        float ix = (dd * bx - bb * by) / det;
        float iy = (a * by - bb * bx) / det;
        // du = ub - miu = ub - (xs - i) = i - noise
        float dux = ix - nzx;
        float duy = iy - nzy;
        float q = a * dux * dux + 2.0f * bb * dux * duy + dd * duy * duy;
        float trip = fmaxf(sqrtf(sp) - sqrtf(sn) + 1.0f, 0.0f);
        red[0][pib] = trip;
        red[1][pib] = q;
        red[2][pib] = logf(det);
    }
    __syncthreads();
    if (tid == 0) {
        float t = 0.0f, qq = 0.0f, l = 0.0f;
        #pragma unroll
        for (int i = 0; i < 8; ++i) { t += red[0][i]; qq += red[1][i]; l += red[2][i]; }
        blk_out[blockIdx.x * 3 + 0] = t;
        blk_out[blockIdx.x * 3 + 1] = qq;
        blk_out[blockIdx.x * 3 + 2] = l;
    }
}

__global__ __launch_bounds__(256) void gn_final_kernel(
    const float* __restrict__ part, int nblk, float* __restrict__ out) {
    __shared__ double sd[3][256];
    double st = 0.0, sq = 0.0, sl = 0.0;
    for (int i = threadIdx.x; i < nblk; i += 256) {
        st += (double)part[i * 3 + 0];
        sq += (double)part[i * 3 + 1];
        sl += (double)part[i * 3 + 2];
    }
    sd[0][threadIdx.x] = st; sd[1][threadIdx.x] = sq; sd[2][threadIdx.x] = sl;
    __syncthreads();
    for (int s = 128; s > 0; s >>= 1) {
        if (threadIdx.x < s) {
            sd[0][threadIdx.x] += sd[0][threadIdx.x + s];
            sd[1][threadIdx.x] += sd[1][threadIdx.x + s];
            sd[2][threadIdx.x] += sd[2][threadIdx.x + s];
        }
        __syncthreads();
    }
    if (threadIdx.x == 0) {
        double S_t = sd[0][0], S_q = sd[1][0], S_l = sd[2][0];
        double tl = 100.0 * S_t / 8192.0;                       // CONTR_LAMDA * sum(mean)
        double e2 = 4.0 * 8192.0 * 1.8378770664093453 - 0.5 * S_l;  // sum_i B*N*ln(2pi) - 0.5*sum(logdet)
        double gl = 0.3 * (0.5 * S_q + (2.0 / 7.0) * e2);       // GN_LAMDA * sum(e1 + 2*e2/7)
        out[0] = (float)(tl + gl);
        out[1] = (float)tl;
        out[2] = (float)gl;
    }
}

extern "C" void kernel_launch(void* const* d_in, const int* in_sizes, int n_in,
                              void* d_out, int out_size, void* d_ws, size_t ws_size,
                              hipStream_t stream) {
    // setup_inputs() dict order: fa0,fb0,noise0, fa1,fb1,noise1, ..., ma,mb,neg,epoch.
    // Disambiguate vs signature order at runtime via sizes (fa0==fb0 in dict order).
    const bool dict_order = (in_sizes[1] == in_sizes[0]);
    const float* fa[4];
    const float* fb[4];
    const float* nz[4];
    for (int i = 0; i < 4; ++i) {
        if (dict_order) {
            fa[i] = (const float*)d_in[3 * i + 0];
            fb[i] = (const float*)d_in[3 * i + 1];
            nz[i] = (const float*)d_in[3 * i + 2];
        } else {
            fa[i] = (const float*)d_in[i];
            fb[i] = (const float*)d_in[4 + i];
            nz[i] = (const float*)d_in[8 + i];
        }
    }
    const float* ma = (const float*)d_in[12];
    const float* mb = (const float*)d_in[13];
    const float* ng = (const float*)d_in[14];

    float* ws = (float*)d_ws;  // 4096 blocks * 3 floats = 48 KB
    const int Hs[4] = {64, 128, 256, 512};
    const float inv_s[4] = {1.0f / 16.0f, 1.0f / 8.0f, 1.0f / 4.0f, 1.0f / 2.0f};

    const int blocks_per_level = 8192 / 8;  // 1024
    for (int i = 0; i < 4; ++i) {
        gn_level_kernel<<<blocks_per_level, 256, 0, stream>>>(
            fa[i], fb[i], nz[i], ma, mb, ng, Hs[i], inv_s[i],
            ws + (size_t)i * blocks_per_level * 3);
    }
    gn_final_kernel<<<1, 256, 0, stream>>>(ws, 4 * blocks_per_level, (float*)d_out);
}

// Round 2
// 136.292 us; speedup vs baseline: 1.0192x; 1.0192x over previous
//
#include <hip/hip_runtime.h>
#include <math.h>

// GNLoss: 4-level pyramid, triplet + Gauss-Newton loss over 8192 sample points.
// R1: fuse all levels into one launch; vectorized patch loads (float2 / float4)
// to cut L1 line transactions ~2.5x. Lane = channel (32 ch), 8 points/block.

struct BL { int x0, x1, y0, y1; float wx, wy; };
struct LevelPtrs { const float* fa[4]; const float* fb[4]; const float* nz[4]; };

__device__ __forceinline__ float2 load2u(const float* p) { float2 v; __builtin_memcpy(&v, p, 8); return v; }
__device__ __forceinline__ float4 load4u(const float* p) { float4 v; __builtin_memcpy(&v, p, 16); return v; }

__device__ __forceinline__ BL bl_setup(float px, float py, int W, int H) {
    BL r;
    float x = fminf(fmaxf(px, 0.0f), (float)(W - 1));
    float y = fminf(fmaxf(py, 0.0f), (float)(H - 1));
    float fx = floorf(x), fy = floorf(y);
    r.wx = x - fx; r.wy = y - fy;
    r.x0 = (int)fx; r.y0 = (int)fy;
    r.x1 = min(r.x0 + 1, W - 1);
    r.y1 = min(r.y0 + 1, H - 1);
    return r;
}

// Generic (edge-safe) bilinear eval, scalar loads.
__device__ __forceinline__ float bl_eval_slow(const float* __restrict__ f, int W, const BL& s) {
    float v00 = f[s.y0 * W + s.x0];
    float v01 = f[s.y0 * W + s.x1];
    float v10 = f[s.y1 * W + s.x0];
    float v11 = f[s.y1 * W + s.x1];
    float a0 = v00 + s.wx * (v01 - v00);
    float a1 = v10 + s.wx * (v11 - v10);
    return a0 + s.wy * (a1 - a0);
}

// Fast bilinear: requires x1 == x0+1 (i.e. x0 <= W-2). Two float2 row loads.
__device__ __forceinline__ float bl_eval_f(const float* __restrict__ f, int W, const BL& s) {
    if (s.x0 < W - 1) {
        float2 v0 = load2u(f + s.y0 * W + s.x0);
        float2 v1 = load2u(f + s.y1 * W + s.x0);
        float a0 = v0.x + s.wx * (v0.y - v0.x);
        float a1 = v1.x + s.wx * (v1.y - v1.x);
        return a0 + s.wy * (a1 - a0);
    }
    return bl_eval_slow(f, W, s);
}

// Edge-safe Jacobian (central diff of f with edge replication, bilinear sampled).
__device__ __forceinline__ void j_eval_slow(const float* __restrict__ f, int W, int H,
                                            const BL& s, float& Jx, float& Jy) {
    int xR0 = min(s.x0 + 1, W - 1), xL0 = max(s.x0 - 1, 0);
    int xR1 = min(s.x1 + 1, W - 1), xL1 = max(s.x1 - 1, 0);
    int yD0 = min(s.y0 + 1, H - 1), yU0 = max(s.y0 - 1, 0);
    int yD1 = min(s.y1 + 1, H - 1), yU1 = max(s.y1 - 1, 0);
    const float* r0 = f + s.y0 * W;
    const float* r1 = f + s.y1 * W;
    float gx00 = r0[xR0] - r0[xL0];
    float gx01 = r0[xR1] - r0[xL1];
    float gx10 = r1[xR0] - r1[xL0];
    float gx11 = r1[xR1] - r1[xL1];
    float gy00 = f[yD0 * W + s.x0] - f[yU0 * W + s.x0];
    float gy01 = f[yD0 * W + s.x1] - f[yU0 * W + s.x1];
    float gy10 = f[yD1 * W + s.x0] - f[yU1 * W + s.x0];
    float gy11 = f[yD1 * W + s.x1] - f[yU1 * W + s.x1];
    float g0 = gx00 + s.wx * (gx01 - gx00);
    float g1 = gx10 + s.wx * (gx11 - gx10);
    Jx = 0.5f * (g0 + s.wy * (g1 - g0));
    float h0 = gy00 + s.wx * (gy01 - gy00);
    float h1 = gy10 + s.wx * (gy11 - gy10);
    Jy = 0.5f * (h0 + s.wy * (h1 - h0));
}

// Combined f_s + Jx + Jy at xs: interior fast path = 4 unaligned float4 row
// loads covering the 4x4 stencil (cols x0-1..x1+1, rows y0-1..y1+1).
__device__ __forceinline__ void xs_eval(const float* __restrict__ f, int W, int H,
                                        const BL& s, float& fs, float& Jx, float& Jy) {
    if (s.x0 >= 1 && s.x0 <= W - 3 && s.y0 >= 1 && s.y0 <= H - 3) {
        const float* base = f + (s.y0 - 1) * W + (s.x0 - 1);
        float4 vm = load4u(base);           // row y0-1: cols x0-1,x0,x1,x1+1
        float4 v0 = load4u(base + W);       // row y0
        float4 v1 = load4u(base + 2 * W);   // row y1
        float4 v2 = load4u(base + 3 * W);   // row y1+1
        float wx = s.wx, wy = s.wy;
        float a0 = v0.y + wx * (v0.z - v0.y);
        float a1 = v1.y + wx * (v1.z - v1.y);
        fs = a0 + wy * (a1 - a0);
        float gx00 = v0.z - v0.x, gx01 = v0.w - v0.y;
        float gx10 = v1.z - v1.x, gx11 = v1.w - v1.y;
        float gy00 = v1.y - vm.y, gy01 = v1.z - vm.z;
        float gy10 = v2.y - v0.y, gy11 = v2.z - v0.z;
        float g0 = gx00 + wx * (gx01 - gx00);
        float g1 = gx10 + wx * (gx11 - gx10);
        Jx = 0.5f * (g0 + wy * (g1 - g0));
        float h0 = gy00 + wx * (gy01 - gy00);
        float h1 = gy10 + wx * (gy11 - gy10);
        Jy = 0.5f * (h0 + wy * (h1 - h0));
    } else {
        fs = bl_eval_slow(f, W, s);
        j_eval_slow(f, W, H, s, Jx, Jy);
    }
}

__device__ __forceinline__ float warp32_sum(float v) {
    v += __shfl_xor(v, 16);
    v += __shfl_xor(v, 8);
    v += __shfl_xor(v, 4);
    v += __shfl_xor(v, 2);
    v += __shfl_xor(v, 1);
    return v;
}

// One block = 8 points x 32 channels. Grid = 4096; level = blockIdx & 3
// (interleaved so the big 512^2 level's blocks start immediately).
__global__ __launch_bounds__(256) void gn_fused_kernel(
    LevelPtrs P, const float* __restrict__ ma, const float* __restrict__ mb,
    const float* __restrict__ ng, float* __restrict__ blk_out) {
    const int lvl = blockIdx.x & 3;
    const int H = 64 << lvl;
    const int W = H;
    const float inv_s = 0.0625f * (float)(1 << lvl);
    const int tid = threadIdx.x;
    const int c = tid & 31;                      // channel
    const int pib = tid >> 5;                    // point-in-block 0..7
    const int p = (blockIdx.x >> 2) * 8 + pib;   // global point (= b*2048+n)
    const int b = p >> 11;
    const int HW = H * W;
    const float* __restrict__ fac = P.fa[lvl] + (size_t)(b * 32 + c) * HW;
    const float* __restrict__ fbc = P.fb[lvl] + (size_t)(b * 32 + c) * HW;
    const float* __restrict__ noise = P.nz[lvl];

    const int p2 = p * 2;
    const float nzx = noise[p2], nzy = noise[p2 + 1];
    const float pax = ma[p2] * inv_s, pay = ma[p2 + 1] * inv_s;
    const float pbx = mb[p2] * inv_s, pby = mb[p2 + 1] * inv_s;
    const float pnx = ng[p2] * inv_s, pny = ng[p2 + 1] * inv_s;
    const float xsx = nzx + pbx, xsy = nzy + pby;  // xs = noise + ub

    BL sa = bl_setup(pax, pay, W, H);
    BL sb = bl_setup(pbx, pby, W, H);
    BL sg = bl_setup(pnx, pny, W, H);
    BL sx = bl_setup(xsx, xsy, W, H);

    float fav = bl_eval_f(fac, W, sa);   // f_t / anchor
    float fpv = bl_eval_f(fbc, W, sb);   // positive
    float fnv = bl_eval_f(fbc, W, sg);   // negative
    float fsv, Jx, Jy;
    xs_eval(fbc, W, H, sx, fsv, Jx, Jy); // f_s + Jacobian

    float r = fsv - fav;
    float a  = warp32_sum(Jx * Jx);
    float dd = warp32_sum(Jy * Jy);
    float bb = warp32_sum(Jx * Jy);
    float bx = warp32_sum(Jx * r);
    float by = warp32_sum(Jy * r);
    float dfp = fav - fpv, dfn = fav - fnv;
    float sp = warp32_sum(dfp * dfp);
    float sn = warp32_sum(dfn * dfn);

    __shared__ float red[3][8];
    if (c == 0) {
        a += 1e-9f; dd += 1e-9f;
        float det = a * dd - bb * bb;          // > 0 by Cauchy-Schwarz + eps
        float ix = (dd * bx - bb * by) / det;
        float iy = (a * by - bb * bx) / det;
        // du = ub - miu = ub - (xs - i) = i - noise
        float dux = ix - nzx;
        float duy = iy - nzy;
        float q = a * dux * dux + 2.0f * bb * dux * duy + dd * duy * duy;
        float trip = fmaxf(sqrtf(sp) - sqrtf(sn) + 1.0f, 0.0f);
        red[0][pib] = trip;
        red[1][pib] = q;
        red[2][pib] = logf(det);
    }
    __syncthreads();
    if (tid == 0) {
        float t = 0.0f, qq = 0.0f, l = 0.0f;
        #pragma unroll
        for (int i = 0; i < 8; ++i) { t += red[0][i]; qq += red[1][i]; l += red[2][i]; }
        blk_out[blockIdx.x * 3 + 0] = t;
        blk_out[blockIdx.x * 3 + 1] = qq;
        blk_out[blockIdx.x * 3 + 2] = l;
    }
}

__global__ __launch_bounds__(256) void gn_final_kernel(
    const float* __restrict__ part, int nblk, float* __restrict__ out) {
    __shared__ double sd[3][256];
    double st = 0.0, sq = 0.0, sl = 0.0;
    for (int i = threadIdx.x; i < nblk; i += 256) {
        st += (double)part[i * 3 + 0];
        sq += (double)part[i * 3 + 1];
        sl += (double)part[i * 3 + 2];
    }
    sd[0][threadIdx.x] = st; sd[1][threadIdx.x] = sq; sd[2][threadIdx.x] = sl;
    __syncthreads();
    for (int s = 128; s > 0; s >>= 1) {
        if (threadIdx.x < s) {
            sd[0][threadIdx.x] += sd[0][threadIdx.x + s];
            sd[1][threadIdx.x] += sd[1][threadIdx.x + s];
            sd[2][threadIdx.x] += sd[2][threadIdx.x + s];
        }
        __syncthreads();
    }
    if (threadIdx.x == 0) {
        double S_t = sd[0][0], S_q = sd[1][0], S_l = sd[2][0];
        double tl = 100.0 * S_t / 8192.0;                           // CONTR_LAMDA * sum(mean)
        double e2 = 4.0 * 8192.0 * 1.8378770664093453 - 0.5 * S_l;  // sum_i B*N*ln(2pi) - 0.5*sum(logdet)
        double gl = 0.3 * (0.5 * S_q + (2.0 / 7.0) * e2);           // GN_LAMDA * sum(e1 + 2*e2/7)
        out[0] = (float)(tl + gl);
        out[1] = (float)tl;
        out[2] = (float)gl;
    }
}

extern "C" void kernel_launch(void* const* d_in, const int* in_sizes, int n_in,
                              void* d_out, int out_size, void* d_ws, size_t ws_size,
                              hipStream_t stream) {
    // setup_inputs() dict order: fa0,fb0,noise0, fa1,fb1,noise1, ..., ma,mb,neg,epoch.
    // Disambiguate vs signature order at runtime via sizes (fa0==fb0 in dict order).
    const bool dict_order = (in_sizes[1] == in_sizes[0]);
    LevelPtrs P;
    for (int i = 0; i < 4; ++i) {
        if (dict_order) {
            P.fa[i] = (const float*)d_in[3 * i + 0];
            P.fb[i] = (const float*)d_in[3 * i + 1];
            P.nz[i] = (const float*)d_in[3 * i + 2];
        } else {
            P.fa[i] = (const float*)d_in[i];
            P.fb[i] = (const float*)d_in[4 + i];
            P.nz[i] = (const float*)d_in[8 + i];
        }
    }
    const float* ma = (const float*)d_in[12];
    const float* mb = (const float*)d_in[13];
    const float* ng = (const float*)d_in[14];

    float* ws = (float*)d_ws;  // 4096 blocks * 3 floats = 48 KB
    const int nblk = 4096;     // 4 levels x 1024 point-blocks, interleaved
    gn_fused_kernel<<<nblk, 256, 0, stream>>>(P, ma, mb, ng, ws);
    gn_final_kernel<<<1, 256, 0, stream>>>(ws, nblk, (float*)d_out);
}

// Round 3
// 132.995 us; speedup vs baseline: 1.0445x; 1.0248x over previous
//
#include <hip/hip_runtime.h>
#include <math.h>

// GNLoss: 4-level pyramid, triplet + Gauss-Newton loss over 8192 sample points.
// R2: latency-bound fix — single fast/slow branch per thread with all 10
// vector loads issued back-to-back (max misses in flight), and mixed-level
// blocks (2 points x 4 levels) for uniform block duration / no drain tail.

struct BL { int x0, x1, y0, y1; float wx, wy; };
struct LevelPtrs { const float* fa[4]; const float* fb[4]; const float* nz[4]; };

__device__ __forceinline__ float2 load2u(const float* p) { float2 v; __builtin_memcpy(&v, p, 8); return v; }
__device__ __forceinline__ float4 load4u(const float* p) { float4 v; __builtin_memcpy(&v, p, 16); return v; }

__device__ __forceinline__ BL bl_setup(float px, float py, int W, int H) {
    BL r;
    float x = fminf(fmaxf(px, 0.0f), (float)(W - 1));
    float y = fminf(fmaxf(py, 0.0f), (float)(H - 1));
    float fx = floorf(x), fy = floorf(y);
    r.wx = x - fx; r.wy = y - fy;
    r.x0 = (int)fx; r.y0 = (int)fy;
    r.x1 = min(r.x0 + 1, W - 1);
    r.y1 = min(r.y0 + 1, H - 1);
    return r;
}

// Edge-safe bilinear eval, scalar loads (slow path only).
__device__ __forceinline__ float bl_eval_slow(const float* __restrict__ f, int W, const BL& s) {
    float v00 = f[s.y0 * W + s.x0];
    float v01 = f[s.y0 * W + s.x1];
    float v10 = f[s.y1 * W + s.x0];
    float v11 = f[s.y1 * W + s.x1];
    float a0 = v00 + s.wx * (v01 - v00);
    float a1 = v10 + s.wx * (v11 - v10);
    return a0 + s.wy * (a1 - a0);
}

// Edge-safe Jacobian (central diff of f with edge replication, bilinear sampled).
__device__ __forceinline__ void j_eval_slow(const float* __restrict__ f, int W, int H,
                                            const BL& s, float& Jx, float& Jy) {
    int xR0 = min(s.x0 + 1, W - 1), xL0 = max(s.x0 - 1, 0);
    int xR1 = min(s.x1 + 1, W - 1), xL1 = max(s.x1 - 1, 0);
    int yD0 = min(s.y0 + 1, H - 1), yU0 = max(s.y0 - 1, 0);
    int yD1 = min(s.y1 + 1, H - 1), yU1 = max(s.y1 - 1, 0);
    const float* r0 = f + s.y0 * W;
    const float* r1 = f + s.y1 * W;
    float gx00 = r0[xR0] - r0[xL0];
    float gx01 = r0[xR1] - r0[xL1];
    float gx10 = r1[xR0] - r1[xL0];
    float gx11 = r1[xR1] - r1[xL1];
    float gy00 = f[yD0 * W + s.x0] - f[yU0 * W + s.x0];
    float gy01 = f[yD0 * W + s.x1] - f[yU0 * W + s.x1];
    float gy10 = f[yD1 * W + s.x0] - f[yU1 * W + s.x0];
    float gy11 = f[yD1 * W + s.x1] - f[yU1 * W + s.x1];
    float g0 = gx00 + s.wx * (gx01 - gx00);
    float g1 = gx10 + s.wx * (gx11 - gx10);
    Jx = 0.5f * (g0 + s.wy * (g1 - g0));
    float h0 = gy00 + s.wx * (gy01 - gy00);
    float h1 = gy10 + s.wx * (gy11 - gy10);
    Jy = 0.5f * (h0 + s.wy * (h1 - h0));
}

__device__ __forceinline__ float warp32_sum(float v) {
    v += __shfl_xor(v, 16);
    v += __shfl_xor(v, 8);
    v += __shfl_xor(v, 4);
    v += __shfl_xor(v, 2);
    v += __shfl_xor(v, 1);
    return v;
}

// Block = 256 threads = 8 (pt,lvl) tasks x 32 channels. Each block covers
// points {2i, 2i+1} at all 4 levels: pib>>1 = level, pib&1 = point offset.
// A wave (64 lanes) = 2 tasks of the SAME level -> branch near-uniform.
__global__ __launch_bounds__(256) void gn_fused_kernel(
    LevelPtrs P, const float* __restrict__ ma, const float* __restrict__ mb,
    const float* __restrict__ ng, float* __restrict__ blk_out) {
    const int tid = threadIdx.x;
    const int c = tid & 31;                      // channel
    const int pib = tid >> 5;                    // task-in-block 0..7
    const int lvl = pib >> 1;
    const int p = blockIdx.x * 2 + (pib & 1);    // global point (= b*2048+n)
    const int H = 64 << lvl;
    const int W = H;
    const float inv_s = 0.0625f * (float)(1 << lvl);
    const int b = p >> 11;
    const int HW = H * W;
    const float* __restrict__ fac = P.fa[lvl] + (size_t)(b * 32 + c) * HW;
    const float* __restrict__ fbc = P.fb[lvl] + (size_t)(b * 32 + c) * HW;
    const float* __restrict__ noise = P.nz[lvl];

    const int p2 = p * 2;
    const float nzx = noise[p2], nzy = noise[p2 + 1];
    const float pax = ma[p2] * inv_s, pay = ma[p2 + 1] * inv_s;
    const float pbx = mb[p2] * inv_s, pby = mb[p2 + 1] * inv_s;
    const float pnx = ng[p2] * inv_s, pny = ng[p2 + 1] * inv_s;
    const float xsx = nzx + pbx, xsy = nzy + pby;  // xs = noise + ub

    BL sa = bl_setup(pax, pay, W, H);
    BL sb = bl_setup(pbx, pby, W, H);
    BL sg = bl_setup(pnx, pny, W, H);
    BL sx = bl_setup(xsx, xsy, W, H);

    float fav, fpv, fnv, fsv, Jx, Jy;
    // fast iff all four sites can use straight-line vector loads
    const bool fast = (sa.x0 < W - 1) & (sb.x0 < W - 1) & (sg.x0 < W - 1) &
                      (sx.x0 >= 1) & (sx.x0 <= W - 3) & (sx.y0 >= 1) & (sx.y0 <= H - 3);
    if (fast) {
        // ---- issue ALL 10 loads back-to-back (one waitcnt batch) ----
        const float* a0p = fac + sa.y0 * W + sa.x0;
        const float* a1p = fac + sa.y1 * W + sa.x0;
        const float* b0p = fbc + sb.y0 * W + sb.x0;
        const float* b1p = fbc + sb.y1 * W + sb.x0;
        const float* g0p = fbc + sg.y0 * W + sg.x0;
        const float* g1p = fbc + sg.y1 * W + sg.x0;
        const float* xbp = fbc + (sx.y0 - 1) * W + (sx.x0 - 1);
        float2 va0 = load2u(a0p);
        float2 va1 = load2u(a1p);
        float2 vb0 = load2u(b0p);
        float2 vb1 = load2u(b1p);
        float2 vg0 = load2u(g0p);
        float2 vg1 = load2u(g1p);
        float4 xm = load4u(xbp);             // row y0-1: cols x0-1,x0,x1,x1+1
        float4 x0 = load4u(xbp + W);         // row y0
        float4 x1 = load4u(xbp + 2 * W);     // row y1
        float4 x2 = load4u(xbp + 3 * W);     // row y1+1
        // ---- consume ----
        {
            float t0 = va0.x + sa.wx * (va0.y - va0.x);
            float t1 = va1.x + sa.wx * (va1.y - va1.x);
            fav = t0 + sa.wy * (t1 - t0);
        }
        {
            float t0 = vb0.x + sb.wx * (vb0.y - vb0.x);
            float t1 = vb1.x + sb.wx * (vb1.y - vb1.x);
            fpv = t0 + sb.wy * (t1 - t0);
        }
        {
            float t0 = vg0.x + sg.wx * (vg0.y - vg0.x);
            float t1 = vg1.x + sg.wx * (vg1.y - vg1.x);
            fnv = t0 + sg.wy * (t1 - t0);
        }
        {
            float wx = sx.wx, wy = sx.wy;
            float t0 = x0.y + wx * (x0.z - x0.y);
            float t1 = x1.y + wx * (x1.z - x1.y);
            fsv = t0 + wy * (t1 - t0);
            float gx00 = x0.z - x0.x, gx01 = x0.w - x0.y;
            float gx10 = x1.z - x1.x, gx11 = x1.w - x1.y;
            float gy00 = x1.y - xm.y, gy01 = x1.z - xm.z;
            float gy10 = x2.y - x0.y, gy11 = x2.z - x0.z;
            float g0 = gx00 + wx * (gx01 - gx00);
            float g1 = gx10 + wx * (gx11 - gx10);
            Jx = 0.5f * (g0 + wy * (g1 - g0));
            float h0 = gy00 + wx * (gy01 - gy00);
            float h1 = gy10 + wx * (gy11 - gy10);
            Jy = 0.5f * (h0 + wy * (h1 - h0));
        }
    } else {
        fav = bl_eval_slow(fac, W, sa);
        fpv = bl_eval_slow(fbc, W, sb);
        fnv = bl_eval_slow(fbc, W, sg);
        fsv = bl_eval_slow(fbc, W, sx);
        j_eval_slow(fbc, W, H, sx, Jx, Jy);
    }

    float r = fsv - fav;
    float a  = warp32_sum(Jx * Jx);
    float dd = warp32_sum(Jy * Jy);
    float bb = warp32_sum(Jx * Jy);
    float bx = warp32_sum(Jx * r);
    float by = warp32_sum(Jy * r);
    float dfp = fav - fpv, dfn = fav - fnv;
    float sp = warp32_sum(dfp * dfp);
    float sn = warp32_sum(dfn * dfn);

    __shared__ float red[3][8];
    if (c == 0) {
        a += 1e-9f; dd += 1e-9f;
        float det = a * dd - bb * bb;          // > 0 by Cauchy-Schwarz + eps
        float ix = (dd * bx - bb * by) / det;
        float iy = (a * by - bb * bx) / det;
        // du = ub - miu = ub - (xs - i) = i - noise
        float dux = ix - nzx;
        float duy = iy - nzy;
        float q = a * dux * dux + 2.0f * bb * dux * duy + dd * duy * duy;
        float trip = fmaxf(sqrtf(sp) - sqrtf(sn) + 1.0f, 0.0f);
        red[0][pib] = trip;
        red[1][pib] = q;
        red[2][pib] = logf(det);
    }
    __syncthreads();
    // All per-task scalars enter the global sums with level-independent
    // weights, so mixing levels inside a block is sum-safe.
    if (tid == 0) {
        float t = 0.0f, qq = 0.0f, l = 0.0f;
        #pragma unroll
        for (int i = 0; i < 8; ++i) { t += red[0][i]; qq += red[1][i]; l += red[2][i]; }
        blk_out[blockIdx.x * 3 + 0] = t;
        blk_out[blockIdx.x * 3 + 1] = qq;
        blk_out[blockIdx.x * 3 + 2] = l;
    }
}

__global__ __launch_bounds__(256) void gn_final_kernel(
    const float* __restrict__ part, int nblk, float* __restrict__ out) {
    __shared__ double sd[3][256];
    double st = 0.0, sq = 0.0, sl = 0.0;
    for (int i = threadIdx.x; i < nblk; i += 256) {
        st += (double)part[i * 3 + 0];
        sq += (double)part[i * 3 + 1];
        sl += (double)part[i * 3 + 2];
    }
    sd[0][threadIdx.x] = st; sd[1][threadIdx.x] = sq; sd[2][threadIdx.x] = sl;
    __syncthreads();
    for (int s = 128; s > 0; s >>= 1) {
        if (threadIdx.x < s) {
            sd[0][threadIdx.x] += sd[0][threadIdx.x + s];
            sd[1][threadIdx.x] += sd[1][threadIdx.x + s];
            sd[2][threadIdx.x] += sd[2][threadIdx.x + s];
        }
        __syncthreads();
    }
    if (threadIdx.x == 0) {
        double S_t = sd[0][0], S_q = sd[1][0], S_l = sd[2][0];
        double tl = 100.0 * S_t / 8192.0;                           // CONTR_LAMDA * sum(mean)
        double e2 = 4.0 * 8192.0 * 1.8378770664093453 - 0.5 * S_l;  // sum_i B*N*ln(2pi) - 0.5*sum(logdet)
        double gl = 0.3 * (0.5 * S_q + (2.0 / 7.0) * e2);           // GN_LAMDA * sum(e1 + 2*e2/7)
        out[0] = (float)(tl + gl);
        out[1] = (float)tl;
        out[2] = (float)gl;
    }
}

extern "C" void kernel_launch(void* const* d_in, const int* in_sizes, int n_in,
                              void* d_out, int out_size, void* d_ws, size_t ws_size,
                              hipStream_t stream) {
    // setup_inputs() dict order: fa0,fb0,noise0, fa1,fb1,noise1, ..., ma,mb,neg,epoch.
    // Disambiguate vs signature order at runtime via sizes (fa0==fb0 in dict order).
    const bool dict_order = (in_sizes[1] == in_sizes[0]);
    LevelPtrs P;
    for (int i = 0; i < 4; ++i) {
        if (dict_order) {
            P.fa[i] = (const float*)d_in[3 * i + 0];
            P.fb[i] = (const float*)d_in[3 * i + 1];
            P.nz[i] = (const float*)d_in[3 * i + 2];
        } else {
            P.fa[i] = (const float*)d_in[i];
            P.fb[i] = (const float*)d_in[4 + i];
            P.nz[i] = (const float*)d_in[8 + i];
        }
    }
    const float* ma = (const float*)d_in[12];
    const float* mb = (const float*)d_in[13];
    const float* ng = (const float*)d_in[14];

    float* ws = (float*)d_ws;  // 4096 blocks * 3 floats = 48 KB
    const int nblk = 4096;     // 4096 blocks x (2 points x 4 levels)
    gn_fused_kernel<<<nblk, 256, 0, stream>>>(P, ma, mb, ng, ws);
    gn_final_kernel<<<1, 256, 0, stream>>>(ws, nblk, (float*)d_out);
}

// Round 4
// 107.790 us; speedup vs baseline: 1.2887x; 1.2338x over previous
//
#include <hip/hip_runtime.h>
#include <math.h>

// GNLoss: 4-level pyramid, triplet + Gauss-Newton loss over 8192 sample points.
// R3: locality attack on the 441 MB line-granularity fetch — Morton-sort points
// by mb per batch (4 bitonic blocks) + XCD-aware block swizzle so each XCD's L2
// sees a compact spatial cluster -> cross-point 128B-line sharing at lvl2/lvl3.

struct BL { int x0, x1, y0, y1; float wx, wy; };
struct LevelPtrs { const float* fa[4]; const float* fb[4]; const float* nz[4]; };

__device__ __forceinline__ float2 load2u(const float* p) { float2 v; __builtin_memcpy(&v, p, 8); return v; }
__device__ __forceinline__ float4 load4u(const float* p) { float4 v; __builtin_memcpy(&v, p, 16); return v; }

__device__ __forceinline__ BL bl_setup(float px, float py, int W, int H) {
    BL r;
    float x = fminf(fmaxf(px, 0.0f), (float)(W - 1));
    float y = fminf(fmaxf(py, 0.0f), (float)(H - 1));
    float fx = floorf(x), fy = floorf(y);
    r.wx = x - fx; r.wy = y - fy;
    r.x0 = (int)fx; r.y0 = (int)fy;
    r.x1 = min(r.x0 + 1, W - 1);
    r.y1 = min(r.y0 + 1, H - 1);
    return r;
}

__device__ __forceinline__ float bl_eval_slow(const float* __restrict__ f, int W, const BL& s) {
    float v00 = f[s.y0 * W + s.x0];
    float v01 = f[s.y0 * W + s.x1];
    float v10 = f[s.y1 * W + s.x0];
    float v11 = f[s.y1 * W + s.x1];
    float a0 = v00 + s.wx * (v01 - v00);
    float a1 = v10 + s.wx * (v11 - v10);
    return a0 + s.wy * (a1 - a0);
}

__device__ __forceinline__ void j_eval_slow(const float* __restrict__ f, int W, int H,
                                            const BL& s, float& Jx, float& Jy) {
    int xR0 = min(s.x0 + 1, W - 1), xL0 = max(s.x0 - 1, 0);
    int xR1 = min(s.x1 + 1, W - 1), xL1 = max(s.x1 - 1, 0);
    int yD0 = min(s.y0 + 1, H - 1), yU0 = max(s.y0 - 1, 0);
    int yD1 = min(s.y1 + 1, H - 1), yU1 = max(s.y1 - 1, 0);
    const float* r0 = f + s.y0 * W;
    const float* r1 = f + s.y1 * W;
    float gx00 = r0[xR0] - r0[xL0];
    float gx01 = r0[xR1] - r0[xL1];
    float gx10 = r1[xR0] - r1[xL0];
    float gx11 = r1[xR1] - r1[xL1];
    float gy00 = f[yD0 * W + s.x0] - f[yU0 * W + s.x0];
    float gy01 = f[yD0 * W + s.x1] - f[yU0 * W + s.x1];
    float gy10 = f[yD1 * W + s.x0] - f[yU1 * W + s.x0];
    float gy11 = f[yD1 * W + s.x1] - f[yU1 * W + s.x1];
    float g0 = gx00 + s.wx * (gx01 - gx00);
    float g1 = gx10 + s.wx * (gx11 - gx10);
    Jx = 0.5f * (g0 + s.wy * (g1 - g0));
    float h0 = gy00 + s.wx * (gy01 - gy00);
    float h1 = gy10 + s.wx * (gy11 - gy10);
    Jy = 0.5f * (h0 + s.wy * (h1 - h0));
}

__device__ __forceinline__ float warp32_sum(float v) {
    v += __shfl_xor(v, 16);
    v += __shfl_xor(v, 8);
    v += __shfl_xor(v, 4);
    v += __shfl_xor(v, 2);
    v += __shfl_xor(v, 1);
    return v;
}

// Morton-sort the 2048 points of one batch by mb coords (10+10 bit interleave).
// One block per batch; bitonic sort of (key<<11 | idx) in LDS.
__global__ __launch_bounds__(1024) void sort_points_kernel(
    const float* __restrict__ mb, int* __restrict__ perm) {
    const int b = blockIdx.x;
    __shared__ unsigned int keys[2048];
    const float* mbb = mb + (size_t)b * 2048 * 2;
    for (int i = threadIdx.x; i < 2048; i += 1024) {
        int ix = min(max((int)mbb[i * 2 + 0], 0), 1023);
        int iy = min(max((int)mbb[i * 2 + 1], 0), 1023);
        unsigned m = 0;
        #pragma unroll
        for (int t = 0; t < 10; ++t)
            m |= (((unsigned)(ix >> t) & 1u) << (2 * t)) | (((unsigned)(iy >> t) & 1u) << (2 * t + 1));
        keys[i] = (m << 11) | (unsigned)i;   // 20b morton + 11b index
    }
    __syncthreads();
    for (unsigned k = 2; k <= 2048; k <<= 1) {
        for (unsigned j = k >> 1; j > 0; j >>= 1) {
            unsigned t = threadIdx.x;
            unsigned i1 = 2 * t - (t & (j - 1));
            unsigned i2 = i1 + j;
            bool up = ((i1 & k) == 0);
            unsigned a = keys[i1], c = keys[i2];
            if ((a > c) == up) { keys[i1] = c; keys[i2] = a; }
            __syncthreads();
        }
    }
    for (int i = threadIdx.x; i < 2048; i += 1024)
        perm[b * 2048 + i] = (int)(keys[i] & 2047u);
}

// Block = 256 threads = 8 (pt,lvl) tasks x 32 channels; block covers sorted
// ranks {2s, 2s+1} at all 4 levels (wave = 2 tasks of same level). XCD swizzle:
// block bid -> s = (bid&7)*512 + bid>>3, so each XCD owns a contiguous sorted
// (i.e. spatially compact) range of points.
__global__ __launch_bounds__(256) void gn_fused_kernel(
    LevelPtrs P, const float* __restrict__ ma, const float* __restrict__ mb,
    const float* __restrict__ ng, const int* __restrict__ perm,
    float* __restrict__ blk_out) {
    const int tid = threadIdx.x;
    const int c = tid & 31;                      // channel
    const int pib = tid >> 5;                    // task-in-block 0..7
    const int lvl = pib >> 1;
    const int bid = blockIdx.x;
    const int s_blk = ((bid & 7) << 9) + (bid >> 3);   // XCD-contiguous swizzle (4096 blocks)
    const int p = s_blk * 2 + (pib & 1);         // sorted rank 0..8191
    const int b = p >> 11;                       // batch (perm is per-batch)
    const int n = perm ? perm[p] : (p & 2047);   // original point index in batch
    const int q = (b << 11) + n;                 // flat point index
    const int H = 64 << lvl;
    const int W = H;
    const float inv_s = 0.0625f * (float)(1 << lvl);
    const int HW = H * W;
    const float* __restrict__ fac = P.fa[lvl] + (size_t)(b * 32 + c) * HW;
    const float* __restrict__ fbc = P.fb[lvl] + (size_t)(b * 32 + c) * HW;
    const float* __restrict__ noise = P.nz[lvl];

    const int p2 = q * 2;
    const float nzx = noise[p2], nzy = noise[p2 + 1];
    const float pax = ma[p2] * inv_s, pay = ma[p2 + 1] * inv_s;
    const float pbx = mb[p2] * inv_s, pby = mb[p2 + 1] * inv_s;
    const float pnx = ng[p2] * inv_s, pny = ng[p2 + 1] * inv_s;
    const float xsx = nzx + pbx, xsy = nzy + pby;  // xs = noise + ub

    BL sa = bl_setup(pax, pay, W, H);
    BL sb = bl_setup(pbx, pby, W, H);
    BL sg = bl_setup(pnx, pny, W, H);
    BL sx = bl_setup(xsx, xsy, W, H);

    float fav, fpv, fnv, fsv, Jx, Jy;
    const bool fast = (sa.x0 < W - 1) & (sb.x0 < W - 1) & (sg.x0 < W - 1) &
                      (sx.x0 >= 1) & (sx.x0 <= W - 3) & (sx.y0 >= 1) & (sx.y0 <= H - 3);
    if (fast) {
        // ---- issue ALL 10 loads back-to-back (one waitcnt batch) ----
        const float* a0p = fac + sa.y0 * W + sa.x0;
        const float* a1p = fac + sa.y1 * W + sa.x0;
        const float* b0p = fbc + sb.y0 * W + sb.x0;
        const float* b1p = fbc + sb.y1 * W + sb.x0;
        const float* g0p = fbc + sg.y0 * W + sg.x0;
        const float* g1p = fbc + sg.y1 * W + sg.x0;
        const float* xbp = fbc + (sx.y0 - 1) * W + (sx.x0 - 1);
        float2 va0 = load2u(a0p);
        float2 va1 = load2u(a1p);
        float2 vb0 = load2u(b0p);
        float2 vb1 = load2u(b1p);
        float2 vg0 = load2u(g0p);
        float2 vg1 = load2u(g1p);
        float4 xm = load4u(xbp);             // row y0-1: cols x0-1,x0,x1,x1+1
        float4 x0 = load4u(xbp + W);         // row y0
        float4 x1 = load4u(xbp + 2 * W);     // row y1
        float4 x2 = load4u(xbp + 3 * W);     // row y1+1
        // ---- consume ----
        {
            float t0 = va0.x + sa.wx * (va0.y - va0.x);
            float t1 = va1.x + sa.wx * (va1.y - va1.x);
            fav = t0 + sa.wy * (t1 - t0);
        }
        {
            float t0 = vb0.x + sb.wx * (vb0.y - vb0.x);
            float t1 = vb1.x + sb.wx * (vb1.y - vb1.x);
            fpv = t0 + sb.wy * (t1 - t0);
        }
        {
            float t0 = vg0.x + sg.wx * (vg0.y - vg0.x);
            float t1 = vg1.x + sg.wx * (vg1.y - vg1.x);
            fnv = t0 + sg.wy * (t1 - t0);
        }
        {
            float wx = sx.wx, wy = sx.wy;
            float t0 = x0.y + wx * (x0.z - x0.y);
            float t1 = x1.y + wx * (x1.z - x1.y);
            fsv = t0 + wy * (t1 - t0);
            float gx00 = x0.z - x0.x, gx01 = x0.w - x0.y;
            float gx10 = x1.z - x1.x, gx11 = x1.w - x1.y;
            float gy00 = x1.y - xm.y, gy01 = x1.z - xm.z;
            float gy10 = x2.y - x0.y, gy11 = x2.z - x0.z;
            float g0 = gx00 + wx * (gx01 - gx00);
            float g1 = gx10 + wx * (gx11 - gx10);
            Jx = 0.5f * (g0 + wy * (g1 - g0));
            float h0 = gy00 + wx * (gy01 - gy00);
            float h1 = gy10 + wx * (gy11 - gy10);
            Jy = 0.5f * (h0 + wy * (h1 - h0));
        }
    } else {
        fav = bl_eval_slow(fac, W, sa);
        fpv = bl_eval_slow(fbc, W, sb);
        fnv = bl_eval_slow(fbc, W, sg);
        fsv = bl_eval_slow(fbc, W, sx);
        j_eval_slow(fbc, W, H, sx, Jx, Jy);
    }

    float r = fsv - fav;
    float a  = warp32_sum(Jx * Jx);
    float dd = warp32_sum(Jy * Jy);
    float bb = warp32_sum(Jx * Jy);
    float bx = warp32_sum(Jx * r);
    float by = warp32_sum(Jy * r);
    float dfp = fav - fpv, dfn = fav - fnv;
    float sp = warp32_sum(dfp * dfp);
    float sn = warp32_sum(dfn * dfn);

    __shared__ float red[3][8];
    if (c == 0) {
        a += 1e-9f; dd += 1e-9f;
        float det = a * dd - bb * bb;          // > 0 by Cauchy-Schwarz + eps
        float ix = (dd * bx - bb * by) / det;
        float iy = (a * by - bb * bx) / det;
        // du = ub - miu = ub - (xs - i) = i - noise
        float dux = ix - nzx;
        float duy = iy - nzy;
        float qv = a * dux * dux + 2.0f * bb * dux * duy + dd * duy * duy;
        float trip = fmaxf(sqrtf(sp) - sqrtf(sn) + 1.0f, 0.0f);
        red[0][pib] = trip;
        red[1][pib] = qv;
        red[2][pib] = logf(det);
    }
    __syncthreads();
    if (tid == 0) {
        float t = 0.0f, qq = 0.0f, l = 0.0f;
        #pragma unroll
        for (int i = 0; i < 8; ++i) { t += red[0][i]; qq += red[1][i]; l += red[2][i]; }
        blk_out[bid * 3 + 0] = t;
        blk_out[bid * 3 + 1] = qq;
        blk_out[bid * 3 + 2] = l;
    }
}

__global__ __launch_bounds__(256) void gn_final_kernel(
    const float* __restrict__ part, int nblk, float* __restrict__ out) {
    __shared__ double sd[3][256];
    double st = 0.0, sq = 0.0, sl = 0.0;
    for (int i = threadIdx.x; i < nblk; i += 256) {
        st += (double)part[i * 3 + 0];
        sq += (double)part[i * 3 + 1];
        sl += (double)part[i * 3 + 2];
    }
    sd[0][threadIdx.x] = st; sd[1][threadIdx.x] = sq; sd[2][threadIdx.x] = sl;
    __syncthreads();
    for (int s = 128; s > 0; s >>= 1) {
        if (threadIdx.x < s) {
            sd[0][threadIdx.x] += sd[0][threadIdx.x + s];
            sd[1][threadIdx.x] += sd[1][threadIdx.x + s];
            sd[2][threadIdx.x] += sd[2][threadIdx.x + s];
        }
        __syncthreads();
    }
    if (threadIdx.x == 0) {
        double S_t = sd[0][0], S_q = sd[1][0], S_l = sd[2][0];
        double tl = 100.0 * S_t / 8192.0;                           // CONTR_LAMDA * sum(mean)
        double e2 = 4.0 * 8192.0 * 1.8378770664093453 - 0.5 * S_l;  // sum_i B*N*ln(2pi) - 0.5*sum(logdet)
        double gl = 0.3 * (0.5 * S_q + (2.0 / 7.0) * e2);           // GN_LAMDA * sum(e1 + 2*e2/7)
        out[0] = (float)(tl + gl);
        out[1] = (float)tl;
        out[2] = (float)gl;
    }
}

extern "C" void kernel_launch(void* const* d_in, const int* in_sizes, int n_in,
                              void* d_out, int out_size, void* d_ws, size_t ws_size,
                              hipStream_t stream) {
    // setup_inputs() dict order: fa0,fb0,noise0, fa1,fb1,noise1, ..., ma,mb,neg,epoch.
    // Disambiguate vs signature order at runtime via sizes (fa0==fb0 in dict order).
    const bool dict_order = (in_sizes[1] == in_sizes[0]);
    LevelPtrs P;
    for (int i = 0; i < 4; ++i) {
        if (dict_order) {
            P.fa[i] = (const float*)d_in[3 * i + 0];
            P.fb[i] = (const float*)d_in[3 * i + 1];
            P.nz[i] = (const float*)d_in[3 * i + 2];
        } else {
            P.fa[i] = (const float*)d_in[i];
            P.fb[i] = (const float*)d_in[4 + i];
            P.nz[i] = (const float*)d_in[8 + i];
        }
    }
    const float* ma = (const float*)d_in[12];
    const float* mb = (const float*)d_in[13];
    const float* ng = (const float*)d_in[14];

    float* ws = (float*)d_ws;
    const int nblk = 4096;
    // ws layout: [0, nblk*3) float partials | [nblk*3, +8192) int perm
    float* partials = ws;
    int* perm = (int*)(ws + nblk * 3);
    const bool do_sort = ws_size >= (size_t)(nblk * 3 + 8192) * 4;

    if (do_sort) sort_points_kernel<<<4, 1024, 0, stream>>>(mb, perm);
    gn_fused_kernel<<<nblk, 256, 0, stream>>>(P, ma, mb, ng, do_sort ? perm : nullptr, partials);
    gn_final_kernel<<<1, 256, 0, stream>>>(partials, nblk, (float*)d_out);
}